// Round 11
// baseline (753.581 us; speedup 1.0000x reference)
//
#include <hip/hip_runtime.h>

#define B_SZ 8192
#define LAT  64
#define ADIM 16
#define DM   128
#define DI   256
#define NST  16
#define NB   2
#define ROWS 16

#define Z_OFF  0
#define RW_OFF (B_SZ * LAT)          /* 524288 */
#define DN_OFF (RW_OFF + B_SZ)       /* 532480 */
#define H_OFF  (DN_OFF + B_SZ)       /* 540672 */

// workspace layout (float offsets). total = 5,537,792 floats = 22.2 MB
#define WS_X0 0                              /* (8192,128) x residual  */
#define WS_XM (B_SZ * DM)                    /* (8192,256) x_main -> y */
#define WS_Z  (WS_XM + B_SZ * DI)            /* (8192,256) gate z      */
#define WS_XP (WS_Z + B_SZ * DI)             /* (8192,36)  B,C,dt pad  */

__device__ __forceinline__ float softplus_f(float v) {
    return fmaxf(v, 0.f) + log1pf(__expf(-fabsf(v)));
}
__device__ __forceinline__ float silu_f(float z) {
    return z / (1.f + __expf(-z));
}
__device__ __forceinline__ float dot4(float4 a, float4 b, float acc) {
    acc = fmaf(a.x, b.x, acc);
    acc = fmaf(a.y, b.y, acc);
    acc = fmaf(a.z, b.z, acc);
    acc = fmaf(a.w, b.w, acc);
    return acc;
}

// ---------------------------------------------------------------------------
// k_pre: fusion -> relu -> LN(blk0) -> in_proj(blk0) -> x_proj(blk0)
// grid 512 x 512 threads, 16 rows/WG
// ---------------------------------------------------------------------------
__global__ __launch_bounds__(512) void k_pre(
    const float* __restrict__ z_t, const int* __restrict__ action,
    const float* __restrict__ a_embed,
    const float* __restrict__ fusion_w, const float* __restrict__ fusion_b,
    const float* __restrict__ norm_g, const float* __restrict__ norm_b,
    const float* __restrict__ in_proj_w, const float* __restrict__ x_proj_w,
    float* __restrict__ ws)
{
    __shared__ __align__(16) float s_in[ROWS][84];
    __shared__ __align__(16) float s_x [ROWS][132];
    __shared__ __align__(16) float s_xn[ROWS][132];
    __shared__ __align__(16) float s_xm[ROWS][260];
    const int t    = threadIdx.x;
    const int row0 = blockIdx.x * ROWS;

    // stage [z_t | a_emb]
    for (int idx = t; idx < ROWS * 80; idx += 512) {
        int r = idx / 80, k = idx - r * 80;
        int row = row0 + r;
        s_in[r][k] = (k < LAT) ? z_t[(size_t)row * LAT + k]
                               : a_embed[action[row] * ADIM + (k - LAT)];
    }
    __syncthreads();

    // fusion matmul + relu -> s_x and ws.X0
    {
        const int j  = t & 127;
        const int rb = t >> 7;                     // 0..3
        const float* wrow = fusion_w + j * 80;
        float acc[4];
        #pragma unroll
        for (int rr = 0; rr < 4; ++rr) acc[rr] = fusion_b[j];
        for (int k = 0; k < 80; k += 4) {
            float4 w4 = *reinterpret_cast<const float4*>(wrow + k);
            #pragma unroll
            for (int rr = 0; rr < 4; ++rr) {
                float4 x4 = *reinterpret_cast<const float4*>(&s_in[rb + 4 * rr][k]);
                acc[rr] = dot4(w4, x4, acc[rr]);
            }
        }
        #pragma unroll
        for (int rr = 0; rr < 4; ++rr) {
            int r = rb + 4 * rr;
            float v = fmaxf(acc[rr], 0.f);
            s_x[r][j] = v;
            ws[WS_X0 + (size_t)(row0 + r) * DM + j] = v;
        }
    }
    __syncthreads();

    // layernorm blk0 -> s_xn   (32 lanes per row)
    {
        const int r = t >> 5, l = t & 31;
        float s = 0.f;
        #pragma unroll
        for (int m = 0; m < 4; ++m) s += s_x[r][l + 32 * m];
        #pragma unroll
        for (int m = 1; m < 32; m <<= 1) s += __shfl_xor(s, m, 32);
        float mu = s * (1.f / 128.f);
        float v = 0.f;
        #pragma unroll
        for (int m = 0; m < 4; ++m) { float d = s_x[r][l + 32 * m] - mu; v = fmaf(d, d, v); }
        #pragma unroll
        for (int m = 1; m < 32; m <<= 1) v += __shfl_xor(v, m, 32);
        float rstd = 1.f / sqrtf(v * (1.f / 128.f) + 1e-5f);
        #pragma unroll
        for (int m = 0; m < 4; ++m) {
            int k = l + 32 * m;
            s_xn[r][k] = (s_x[r][k] - mu) * rstd * norm_g[k] + norm_b[k];
        }
    }
    __syncthreads();

    // in_proj blk0: thread t owns output row t (t<256: x_main, else z)
    {
        const float* w = in_proj_w + (size_t)t * DM;
        float acc[ROWS];
        #pragma unroll
        for (int r = 0; r < ROWS; ++r) acc[r] = 0.f;
        for (int k = 0; k < DM; k += 4) {
            float4 w4 = *reinterpret_cast<const float4*>(w + k);
            #pragma unroll
            for (int r = 0; r < ROWS; ++r) {
                float4 x4 = *reinterpret_cast<const float4*>(&s_xn[r][k]);
                acc[r] = dot4(w4, x4, acc[r]);
            }
        }
        if (t < DI) {
            #pragma unroll
            for (int r = 0; r < ROWS; ++r) {
                s_xm[r][t] = acc[r];
                ws[WS_XM + (size_t)(row0 + r) * DI + t] = acc[r];
            }
        } else {
            #pragma unroll
            for (int r = 0; r < ROWS; ++r)
                ws[WS_Z + (size_t)(row0 + r) * DI + (t - DI)] = acc[r];
        }
    }
    __syncthreads();

    // x_proj blk0 -> ws.XP
    for (int it = t; it < ROWS * 33; it += 512) {
        int r = it / 33, j = it - r * 33;
        const float* w = x_proj_w + (size_t)j * DI;
        float acc = 0.f;
        for (int k = 0; k < DI; k += 4) {
            float4 w4 = *reinterpret_cast<const float4*>(w + k);
            float4 x4 = *reinterpret_cast<const float4*>(&s_xm[r][k]);
            acc = dot4(w4, x4, acc);
        }
        ws[WS_XP + (size_t)(row0 + r) * 36 + j] = acc;
    }
}

// ---------------------------------------------------------------------------
// k_ssm: pure h-state stream. One WG per batch row; thread t = channel d.
// grid 8192 x 256. Reads h, xm, z, xp; writes h_new (d_out) and y*silu(z)
// in-place over ws.XM.
// ---------------------------------------------------------------------------
__global__ __launch_bounds__(256) void k_ssm(
    const float* __restrict__ h_in, const float* __restrict__ log_A,
    const float* __restrict__ dt_bias, const float* __restrict__ Dp,
    float* __restrict__ ws, float* __restrict__ out, int blk)
{
    __shared__ float s_xp[36];
    const int t   = threadIdx.x;
    const int row = blockIdx.x;
    if (t < 36) s_xp[t] = ws[WS_XP + (size_t)row * 36 + t];
    __syncthreads();

    const int d = t;
    const float* lA = log_A + ((size_t)blk * DI + d) * NST;
    float Av[NST];
    #pragma unroll
    for (int n = 0; n < NST; ++n) Av[n] = __expf(lA[n]);

    const float xm    = ws[WS_XM + (size_t)row * DI + d];
    const float zz    = ws[WS_Z  + (size_t)row * DI + d];
    const float delta = softplus_f(s_xp[32] + dt_bias[blk * DI + d]);
    const float dxm   = delta * xm;

    const size_t hoff = ((size_t)(blk * B_SZ + row) * DI + d) * NST;
    const float* hb = h_in + hoff;
    float hv[NST];
    *reinterpret_cast<float4*>(hv + 0)  = *reinterpret_cast<const float4*>(hb + 0);
    *reinterpret_cast<float4*>(hv + 4)  = *reinterpret_cast<const float4*>(hb + 4);
    *reinterpret_cast<float4*>(hv + 8)  = *reinterpret_cast<const float4*>(hb + 8);
    *reinterpret_cast<float4*>(hv + 12) = *reinterpret_cast<const float4*>(hb + 12);

    float y = 0.f;
    #pragma unroll
    for (int n = 0; n < NST; ++n) {
        float ab = __expf(-delta * Av[n]);
        float hn = fmaf(ab, hv[n], dxm * s_xp[n]);
        y = fmaf(hn, s_xp[16 + n], y);
        hv[n] = hn;
    }
    float* ho = out + H_OFF + hoff;
    *reinterpret_cast<float4*>(ho + 0)  = *reinterpret_cast<float4*>(hv + 0);
    *reinterpret_cast<float4*>(ho + 4)  = *reinterpret_cast<float4*>(hv + 4);
    *reinterpret_cast<float4*>(ho + 8)  = *reinterpret_cast<float4*>(hv + 8);
    *reinterpret_cast<float4*>(ho + 12) = *reinterpret_cast<float4*>(hv + 12);

    y = fmaf(Dp[blk * DI + d], xm, y);
    ws[WS_XM + (size_t)row * DI + d] = y * silu_f(zz);
}

// ---------------------------------------------------------------------------
// k_mid: out_proj(blk0)+residual -> LN(blk1) -> in_proj(blk1) -> x_proj(blk1)
// ---------------------------------------------------------------------------
__global__ __launch_bounds__(512) void k_mid(
    const float* __restrict__ norm_g, const float* __restrict__ norm_b,
    const float* __restrict__ in_proj_w, const float* __restrict__ x_proj_w,
    const float* __restrict__ out_proj_w, float* __restrict__ ws)
{
    __shared__ __align__(16) float s_y [ROWS][260];
    __shared__ __align__(16) float s_x [ROWS][132];
    __shared__ __align__(16) float s_xn[ROWS][132];
    __shared__ __align__(16) float s_xm[ROWS][260];
    const int t    = threadIdx.x;
    const int row0 = blockIdx.x * ROWS;

    for (int idx = t; idx < ROWS * 64; idx += 512) {
        int r = idx >> 6, c = (idx & 63) * 4;
        *reinterpret_cast<float4*>(&s_y[r][c]) =
            *reinterpret_cast<const float4*>(&ws[WS_XM + (size_t)(row0 + r) * DI + c]);
    }
    for (int idx = t; idx < ROWS * 32; idx += 512) {
        int r = idx >> 5, c = (idx & 31) * 4;
        *reinterpret_cast<float4*>(&s_x[r][c]) =
            *reinterpret_cast<const float4*>(&ws[WS_X0 + (size_t)(row0 + r) * DM + c]);
    }
    __syncthreads();

    // out_proj blk0 + residual -> s_x and ws.X0 (becomes x1)
    {
        const int j  = t & 127;
        const int rb = t >> 7;
        const float* w = out_proj_w + (size_t)j * DI;
        float acc[4] = {0.f, 0.f, 0.f, 0.f};
        for (int k = 0; k < DI; k += 4) {
            float4 w4 = *reinterpret_cast<const float4*>(w + k);
            #pragma unroll
            for (int rr = 0; rr < 4; ++rr) {
                float4 x4 = *reinterpret_cast<const float4*>(&s_y[rb + 4 * rr][k]);
                acc[rr] = dot4(w4, x4, acc[rr]);
            }
        }
        #pragma unroll
        for (int rr = 0; rr < 4; ++rr) {
            int r = rb + 4 * rr;
            float v = s_x[r][j] + acc[rr];
            s_x[r][j] = v;
            ws[WS_X0 + (size_t)(row0 + r) * DM + j] = v;
        }
    }
    __syncthreads();

    // layernorm blk1
    {
        const int r = t >> 5, l = t & 31;
        const float* ng  = norm_g + DM;
        const float* nbv = norm_b + DM;
        float s = 0.f;
        #pragma unroll
        for (int m = 0; m < 4; ++m) s += s_x[r][l + 32 * m];
        #pragma unroll
        for (int m = 1; m < 32; m <<= 1) s += __shfl_xor(s, m, 32);
        float mu = s * (1.f / 128.f);
        float v = 0.f;
        #pragma unroll
        for (int m = 0; m < 4; ++m) { float d = s_x[r][l + 32 * m] - mu; v = fmaf(d, d, v); }
        #pragma unroll
        for (int m = 1; m < 32; m <<= 1) v += __shfl_xor(v, m, 32);
        float rstd = 1.f / sqrtf(v * (1.f / 128.f) + 1e-5f);
        #pragma unroll
        for (int m = 0; m < 4; ++m) {
            int k = l + 32 * m;
            s_xn[r][k] = (s_x[r][k] - mu) * rstd * ng[k] + nbv[k];
        }
    }
    __syncthreads();

    // in_proj blk1
    {
        const float* w = in_proj_w + (size_t)(2 * DI * DM) + (size_t)t * DM;
        float acc[ROWS];
        #pragma unroll
        for (int r = 0; r < ROWS; ++r) acc[r] = 0.f;
        for (int k = 0; k < DM; k += 4) {
            float4 w4 = *reinterpret_cast<const float4*>(w + k);
            #pragma unroll
            for (int r = 0; r < ROWS; ++r) {
                float4 x4 = *reinterpret_cast<const float4*>(&s_xn[r][k]);
                acc[r] = dot4(w4, x4, acc[r]);
            }
        }
        if (t < DI) {
            #pragma unroll
            for (int r = 0; r < ROWS; ++r) {
                s_xm[r][t] = acc[r];
                ws[WS_XM + (size_t)(row0 + r) * DI + t] = acc[r];
            }
        } else {
            #pragma unroll
            for (int r = 0; r < ROWS; ++r)
                ws[WS_Z + (size_t)(row0 + r) * DI + (t - DI)] = acc[r];
        }
    }
    __syncthreads();

    // x_proj blk1
    for (int it = t; it < ROWS * 33; it += 512) {
        int r = it / 33, j = it - r * 33;
        const float* w = x_proj_w + (size_t)(33 * DI) + (size_t)j * DI;
        float acc = 0.f;
        for (int k = 0; k < DI; k += 4) {
            float4 w4 = *reinterpret_cast<const float4*>(w + k);
            float4 x4 = *reinterpret_cast<const float4*>(&s_xm[r][k]);
            acc = dot4(w4, x4, acc);
        }
        ws[WS_XP + (size_t)(row0 + r) * 36 + j] = acc;
    }
}

// ---------------------------------------------------------------------------
// k_post: out_proj(blk1)+residual -> heads (z_next, reward, done)
// ---------------------------------------------------------------------------
__global__ __launch_bounds__(512) void k_post(
    const float* __restrict__ out_proj_w,
    const float* __restrict__ ns_w1, const float* __restrict__ ns_b1,
    const float* __restrict__ ns_w2, const float* __restrict__ ns_b2,
    const float* __restrict__ rw_w1, const float* __restrict__ rw_b1,
    const float* __restrict__ rw_w2, const float* __restrict__ rw_b2,
    const float* __restrict__ dn_w1, const float* __restrict__ dn_b1,
    const float* __restrict__ dn_w2, const float* __restrict__ dn_b2,
    float* __restrict__ ws, float* __restrict__ out)
{
    __shared__ __align__(16) float s_y [ROWS][260];  // y1, then rw|dn hidden
    __shared__ __align__(16) float s_x [ROWS][132];  // x2
    __shared__ __align__(16) float s_xn[ROWS][132];  // ns hidden
    const int t    = threadIdx.x;
    const int row0 = blockIdx.x * ROWS;

    for (int idx = t; idx < ROWS * 64; idx += 512) {
        int r = idx >> 6, c = (idx & 63) * 4;
        *reinterpret_cast<float4*>(&s_y[r][c]) =
            *reinterpret_cast<const float4*>(&ws[WS_XM + (size_t)(row0 + r) * DI + c]);
    }
    for (int idx = t; idx < ROWS * 32; idx += 512) {
        int r = idx >> 5, c = (idx & 31) * 4;
        *reinterpret_cast<float4*>(&s_x[r][c]) =
            *reinterpret_cast<const float4*>(&ws[WS_X0 + (size_t)(row0 + r) * DM + c]);
    }
    __syncthreads();

    // out_proj blk1 + residual -> s_x
    {
        const int j  = t & 127;
        const int rb = t >> 7;
        const float* w = out_proj_w + (size_t)(DM * DI) + (size_t)j * DI;
        float acc[4] = {0.f, 0.f, 0.f, 0.f};
        for (int k = 0; k < DI; k += 4) {
            float4 w4 = *reinterpret_cast<const float4*>(w + k);
            #pragma unroll
            for (int rr = 0; rr < 4; ++rr) {
                float4 x4 = *reinterpret_cast<const float4*>(&s_y[rb + 4 * rr][k]);
                acc[rr] = dot4(w4, x4, acc[rr]);
            }
        }
        #pragma unroll
        for (int rr = 0; rr < 4; ++rr) {
            int r = rb + 4 * rr;
            s_x[r][j] += acc[rr];
        }
    }
    __syncthreads();

    // ns hidden (128) -> s_xn
    {
        const int j  = t & 127;
        const int rb = t >> 7;
        const float* w = ns_w1 + (size_t)j * DM;
        float acc[4];
        #pragma unroll
        for (int rr = 0; rr < 4; ++rr) acc[rr] = ns_b1[j];
        for (int k = 0; k < DM; k += 4) {
            float4 w4 = *reinterpret_cast<const float4*>(w + k);
            #pragma unroll
            for (int rr = 0; rr < 4; ++rr) {
                float4 x4 = *reinterpret_cast<const float4*>(&s_x[rb + 4 * rr][k]);
                acc[rr] = dot4(w4, x4, acc[rr]);
            }
        }
        #pragma unroll
        for (int rr = 0; rr < 4; ++rr)
            s_xn[rb + 4 * rr][j] = fmaxf(acc[rr], 0.f);
    }
    // rw / dn hidden (64 each) -> s_y[r][0..63] and s_y[r][128..191]
    {
        const int o   = t & 63;
        const int rb8 = t >> 6;   // 0..7
        const float* wr = rw_w1 + (size_t)o * DM;
        const float* wd = dn_w1 + (size_t)o * DM;
        float accR[2], accD[2];
        #pragma unroll
        for (int m = 0; m < 2; ++m) { accR[m] = rw_b1[o]; accD[m] = dn_b1[o]; }
        for (int k = 0; k < DM; k += 4) {
            float4 w4r = *reinterpret_cast<const float4*>(wr + k);
            float4 w4d = *reinterpret_cast<const float4*>(wd + k);
            #pragma unroll
            for (int m = 0; m < 2; ++m) {
                float4 x4 = *reinterpret_cast<const float4*>(&s_x[rb8 + 8 * m][k]);
                accR[m] = dot4(w4r, x4, accR[m]);
                accD[m] = dot4(w4d, x4, accD[m]);
            }
        }
        #pragma unroll
        for (int m = 0; m < 2; ++m) {
            int r = rb8 + 8 * m;
            s_y[r][o]       = fmaxf(accR[m], 0.f);
            s_y[r][128 + o] = fmaxf(accD[m], 0.f);
        }
    }
    __syncthreads();

    // z_next
    {
        const int o   = t & 63;
        const int rb8 = t >> 6;
        const float* w = ns_w2 + (size_t)o * DM;
        float acc[2];
        #pragma unroll
        for (int m = 0; m < 2; ++m) acc[m] = ns_b2[o];
        for (int k = 0; k < DM; k += 4) {
            float4 w4 = *reinterpret_cast<const float4*>(w + k);
            #pragma unroll
            for (int m = 0; m < 2; ++m) {
                float4 x4 = *reinterpret_cast<const float4*>(&s_xn[rb8 + 8 * m][k]);
                acc[m] = dot4(w4, x4, acc[m]);
            }
        }
        #pragma unroll
        for (int m = 0; m < 2; ++m) {
            int r = rb8 + 8 * m;
            out[Z_OFF + (size_t)(row0 + r) * LAT + o] = acc[m];
        }
    }
    // reward / done
    if (t < 32) {
        const int r    = t & 15;
        const bool isR = (t < 16);
        const float* w2 = isR ? rw_w2 : dn_w2;
        const float  b2 = isR ? rw_b2[0] : dn_b2[0];
        const int    co = isR ? 0 : 128;
        float acc = b2;
        for (int k = 0; k < 64; ++k) acc = fmaf(s_y[r][co + k], w2[k], acc);
        out[(isR ? RW_OFF : DN_OFF) + row0 + r] = acc;
    }
}

extern "C" void kernel_launch(void* const* d_in, const int* in_sizes, int n_in,
                              void* d_out, int out_size, void* d_ws, size_t ws_size,
                              hipStream_t stream) {
    (void)in_sizes; (void)n_in; (void)out_size; (void)ws_size;
    const float* z_t      = (const float*)d_in[0];
    const int*   action   = (const int*)  d_in[1];
    const float* h_in     = (const float*)d_in[2];
    const float* a_embed  = (const float*)d_in[3];
    const float* norm_g   = (const float*)d_in[6];
    const float* norm_b   = (const float*)d_in[7];
    const float* in_w     = (const float*)d_in[8];
    const float* xp_w     = (const float*)d_in[9];
    const float* log_A    = (const float*)d_in[10];
    const float* dt_bias  = (const float*)d_in[11];
    const float* Dp       = (const float*)d_in[12];
    const float* out_w    = (const float*)d_in[13];
    float* ws  = (float*)d_ws;
    float* out = (float*)d_out;

    k_pre<<<B_SZ / ROWS, 512, 0, stream>>>(z_t, action, a_embed,
        (const float*)d_in[4], (const float*)d_in[5], norm_g, norm_b, in_w, xp_w, ws);
    k_ssm<<<B_SZ, 256, 0, stream>>>(h_in, log_A, dt_bias, Dp, ws, out, 0);
    k_mid<<<B_SZ / ROWS, 512, 0, stream>>>(norm_g, norm_b, in_w, xp_w, out_w, ws);
    k_ssm<<<B_SZ, 256, 0, stream>>>(h_in, log_A, dt_bias, Dp, ws, out, 1);
    k_post<<<B_SZ / ROWS, 512, 0, stream>>>(out_w,
        (const float*)d_in[14], (const float*)d_in[15], (const float*)d_in[16], (const float*)d_in[17],
        (const float*)d_in[18], (const float*)d_in[19], (const float*)d_in[20], (const float*)d_in[21],
        (const float*)d_in[22], (const float*)d_in[23], (const float*)d_in[24], (const float*)d_in[25],
        ws, out);
}